// Round 9
// baseline (54.514 us; speedup 1.0000x reference)
//
#include <hip/hip_runtime.h>

#define CSC 2.88539008177792681f  // 2*log2(e)

typedef float v2f __attribute__((ext_vector_type(2)));

__device__ __forceinline__ float fast_exp2(float x) {
  return __builtin_amdgcn_exp2f(x);
}
__device__ __forceinline__ float fast_rcp(float x) {
  return __builtin_amdgcn_rcpf(x);
}
__device__ __forceinline__ v2f vfma(v2f a, v2f b, v2f c) {
  return __builtin_elementwise_fma(a, b, c);
}
__device__ __forceinline__ v2f vsplat(float s) {
  v2f r;
  r[0] = s;
  r[1] = s;
  return r;
}

// Projection: 256 blocks x 256 threads. Blocks 0..127 -> Eq row-major
// [qrow][e]; 128..255 -> EkT4 interleaved-transposed [e/4][col][4] so the
// attention score loop reads one float4 (4 e-values for its k) per e-quad,
// fully coalesced over k.
__global__ __launch_bounds__(256) void proj_kernel(
    const float* __restrict__ query, const float* __restrict__ key,
    const float* __restrict__ weight, float* __restrict__ Eq,
    float* __restrict__ EkT4) {
  __shared__ __align__(16) float rows[16][128];
  __shared__ __align__(16) float tile[16][132];  // +4 pad: conflict-free reads
  int blk = blockIdx.x;
  bool isK = blk >= 128;
  const float* src = isK ? key : query;
  int woff = isK ? 128 : 0;
  int row0 = (isK ? blk - 128 : blk) * 16;
  int tid = threadIdx.x;
#pragma unroll
  for (int i = 0; i < 8; ++i) {
    int f = i * 256 + tid;
    rows[f >> 7][f & 127] = src[(size_t)row0 * 128 + f];
  }
  __syncthreads();
  int e = tid & 127;
  int rh = (tid >> 7) * 8;  // wave-uniform
  float acc[8];
#pragma unroll
  for (int i = 0; i < 8; ++i) acc[i] = 0.f;
  const float4* wrow =
      reinterpret_cast<const float4*>(weight + (size_t)e * 256 + woff);
#pragma unroll 4
  for (int d4 = 0; d4 < 32; ++d4) {
    float4 wv = wrow[d4];
#pragma unroll
    for (int i = 0; i < 8; ++i) {
      float4 rv = *reinterpret_cast<const float4*>(&rows[rh + i][d4 * 4]);
      acc[i] = fmaf(rv.x, wv.x, acc[i]);
      acc[i] = fmaf(rv.y, wv.y, acc[i]);
      acc[i] = fmaf(rv.z, wv.z, acc[i]);
      acc[i] = fmaf(rv.w, wv.w, acc[i]);
    }
  }
  if (!isK) {
#pragma unroll
    for (int i = 0; i < 8; ++i)
      Eq[(size_t)(row0 + rh + i) * 128 + e] = fast_exp2(CSC * acc[i]);
  } else {
#pragma unroll
    for (int i = 0; i < 8; ++i) tile[rh + i][e] = fast_exp2(CSC * acc[i]);
    __syncthreads();
    int kk = tid & 15;
    int e4a = tid >> 4;  // 0..15
#pragma unroll
    for (int h = 0; h < 2; ++h) {
      int ee = e4a + h * 16;  // e-quad index 0..31
      float4 v = *reinterpret_cast<const float4*>(&tile[kk][ee * 4]);
      *reinterpret_cast<float4*>(EkT4 + ((size_t)ee * 2048 + row0 + kk) * 4) =
          v;
    }
  }
}

// Attention partial: grid 1024 = b(2) x qg(128) x kh(4); 256 threads (4 waves)
// Block = 8 q-rows x 256-k slice; thread = 8 q x 1 k x 128 e. eq/vT staged in
// LDS, read as wave-uniform ds_read_b128 BROADCASTS (in-order lgkm -> counted
// waits; zero SMEM in the hot loop). 4 blocks/CU -> 4 independent barrier
// domains. Writes UNNORMALIZED PV partials + exp-sums.
// score' = -2*sum_e vT_e/(1+Eq*Ek); sum(vT) cancels; scores bounded -> no max.
__global__ __launch_bounds__(256, 4) void attn_kernel(
    const float* __restrict__ Eq, const float* __restrict__ EkT4,
    const float* __restrict__ vT, const float* __restrict__ value,
    float* __restrict__ pblk, float* __restrict__ dsum) {
  __shared__ __align__(16) float eq_lds[8][128];  // 4 KB
  __shared__ __align__(16) float vt_lds[128];     // 512 B
  __shared__ __align__(16) float sc[8][256];      // 8 KB p-values
  __shared__ __align__(16) v2f pout[4][8][64];    // 16 KB PV partials
  __shared__ float wsum[4][8];

  int tid = threadIdx.x;
  int lane = tid & 63;
  int w = tid >> 6;
  int bi = blockIdx.x;
  int kh = bi & 3;
  int qg = (bi >> 2) & 127;
  int b = bi >> 9;
  int q0 = qg * 8;
  int k0 = kh * 256;

  // ---- stage eq (8x128) + vT into LDS, coalesced ----
  {
    const float4* eqg =
        reinterpret_cast<const float4*>(Eq + (size_t)(b * 1024 + q0) * 128);
    *reinterpret_cast<float4*>(&eq_lds[tid >> 5][(tid & 31) * 4]) = eqg[tid];
    if (tid < 32)
      *reinterpret_cast<float4*>(&vt_lds[tid * 4]) =
          reinterpret_cast<const float4*>(vT)[tid];
  }
  __syncthreads();

  // ---- scores + exp + row partial sums: thread -> k = k0 + tid ----
  {
    const float4* ekp =
        reinterpret_cast<const float4*>(EkT4) + (size_t)b * 1024 + k0 + tid;
    float acc[8];
#pragma unroll
    for (int q = 0; q < 8; ++q) acc[q] = 0.f;
#pragma unroll 2
    for (int e4 = 0; e4 < 32; ++e4) {
      float4 ek = ekp[(size_t)e4 * 2048];  // streamed, coalesced
      float4 vt4 =
          *reinterpret_cast<const float4*>(&vt_lds[e4 * 4]);  // broadcast
#pragma unroll
      for (int q = 0; q < 8; ++q) {
        float4 eqq =
            *reinterpret_cast<const float4*>(&eq_lds[q][e4 * 4]);  // broadcast
        float A0 = fmaf(eqq.x, ek.x, 1.f);
        float A1 = fmaf(eqq.y, ek.y, 1.f);
        float A2 = fmaf(eqq.z, ek.z, 1.f);
        float A3 = fmaf(eqq.w, ek.w, 1.f);
        float P01 = A0 * A1;
        float P23 = A2 * A3;
        float t01 = fmaf(vt4.x, A1, vt4.y * A0);
        float t23 = fmaf(vt4.z, A3, vt4.w * A2);
        float num = fmaf(t23, P01, t01 * P23);
        acc[q] = fmaf(num, fast_rcp(P01 * P23), acc[q]);
      }
    }
#pragma unroll
    for (int q = 0; q < 8; ++q) {
      float p = fast_exp2(-CSC * acc[q]);
      sc[q][tid] = p;
      float s = p;
#pragma unroll
      for (int off = 32; off; off >>= 1) s += __shfl_xor(s, off);
      if (lane == 0) wsum[w][q] = s;
    }
  }
  __syncthreads();
  if (tid < 8) {
    float s = wsum[0][tid] + wsum[1][tid] + wsum[2][tid] + wsum[3][tid];
    dsum[(size_t)bi * 8 + tid] = s;
  }

  // ---- PV partial: wave w -> local k in [w*64,+64), all 8 q;
  //      lane -> v2f column; p broadcast via ds_read_b128 ----
  {
    int kb = w * 64;
    v2f acc2[8];
#pragma unroll
    for (int q = 0; q < 8; ++q) acc2[q] = vsplat(0.f);
    const v2f* vp = reinterpret_cast<const v2f*>(value) +
                    ((size_t)b * 1024 + k0 + kb) * 64 + lane;
#pragma unroll 2
    for (int k4 = 0; k4 < 16; ++k4) {
      v2f vv0 = vp[(size_t)(k4 * 4 + 0) * 64];
      v2f vv1 = vp[(size_t)(k4 * 4 + 1) * 64];
      v2f vv2 = vp[(size_t)(k4 * 4 + 2) * 64];
      v2f vv3 = vp[(size_t)(k4 * 4 + 3) * 64];
#pragma unroll
      for (int q = 0; q < 8; ++q) {
        float4 pp = *reinterpret_cast<const float4*>(&sc[q][kb + k4 * 4]);
        acc2[q] = vfma(vsplat(pp.x), vv0, acc2[q]);
        acc2[q] = vfma(vsplat(pp.y), vv1, acc2[q]);
        acc2[q] = vfma(vsplat(pp.z), vv2, acc2[q]);
        acc2[q] = vfma(vsplat(pp.w), vv3, acc2[q]);
      }
    }
#pragma unroll
    for (int q = 0; q < 8; ++q) pout[w][q][lane] = acc2[q];
  }
  __syncthreads();

  // ---- 4-way cross-wave reduce -> workspace (unnormalized) ----
  for (int s = tid; s < 512; s += 256) {
    int q = s >> 6;
    int c = s & 63;
    v2f r = pout[0][q][c];
#pragma unroll
    for (int ww = 1; ww < 4; ++ww) r = r + pout[ww][q][c];
    *reinterpret_cast<v2f*>(pblk + (size_t)bi * 1024 + q * 128 + 2 * c) = r;
  }
}

// Combine: sum the 4 k-slice partials, normalize. 256 blocks x 512 threads;
// thread -> one (row, v2f col) of out[2048][128].
__global__ __launch_bounds__(512) void combine_kernel(
    const float* __restrict__ pblk, const float* __restrict__ dsum,
    float* __restrict__ out) {
  int g = blockIdx.x * 512 + threadIdx.x;
  int row = g >> 6;
  int c = g & 63;
  int b = row >> 10;
  int qg = (row >> 3) & 127;
  int q = row & 7;
  int bi0 = b * 512 + qg * 4;
  v2f r = vsplat(0.f);
  float d = 0.f;
#pragma unroll
  for (int kh = 0; kh < 4; ++kh) {
    r = r + *reinterpret_cast<const v2f*>(pblk + (size_t)(bi0 + kh) * 1024 +
                                          q * 128 + 2 * c);
    d += dsum[(size_t)(bi0 + kh) * 8 + q];
  }
  float inv = fast_rcp(d);
  r[0] *= inv;
  r[1] *= inv;
  *reinterpret_cast<v2f*>(out + (size_t)row * 128 + 2 * c) = r;
}

extern "C" void kernel_launch(void* const* d_in, const int* in_sizes, int n_in,
                              void* d_out, int out_size, void* d_ws,
                              size_t ws_size, hipStream_t stream) {
  const float* query = (const float*)d_in[0];
  const float* key = (const float*)d_in[1];
  const float* value = (const float*)d_in[2];
  const float* vT = (const float*)d_in[3];
  const float* weight = (const float*)d_in[4];
  float* out = (float*)d_out;
  float* Eq = (float*)d_ws;      // 2048*128 f32 = 1 MB
  float* EkT4 = Eq + 262144;     // 32 x 2048 x 4 f32 = 1 MB (interleaved-T)
  float* pblk = EkT4 + 262144;   // 1024 x 8 x 128 f32 = 4 MB
  float* dsum = pblk + 1048576;  // 1024 x 8 f32 = 32 KB
  proj_kernel<<<256, 256, 0, stream>>>(query, key, weight, Eq, EkT4);
  attn_kernel<<<1024, 256, 0, stream>>>(Eq, EkT4, vT, value, pblk, dsum);
  combine_kernel<<<256, 512, 0, stream>>>(pblk, dsum, out);
}